// Round 9
// baseline (349.259 us; speedup 1.0000x reference)
//
#include <hip/hip_runtime.h>
#include <cmath>
#include <cfloat>

#define HW_ 16384

__device__ __forceinline__ unsigned f2key(float f){
    unsigned u = __float_as_uint(f);
    return u ^ ((u & 0x80000000u) ? 0xFFFFFFFFu : 0x80000000u);
}
__device__ __forceinline__ float key2f(unsigned k){
    unsigned u = (k & 0x80000000u) ? (k ^ 0x80000000u) : ~k;
    return __uint_as_float(u);
}
__device__ __forceinline__ unsigned short f2bf(float f){
    unsigned u = __float_as_uint(f);
    unsigned r = u + 0x7FFFu + ((u >> 16) & 1u);
    return (unsigned short)(r >> 16);
}
__device__ __forceinline__ float bf2f(unsigned short s){
    return __uint_as_float((unsigned)s << 16);
}
// packed helpers (bf16 pairs in u32; all pooled values >= 0 so u16 order == float order)
__device__ __forceinline__ unsigned pkmax(unsigned a, unsigned b){
    unsigned d;
    asm("v_pk_max_u16 %0, %1, %2" : "=v"(d) : "v"(a), "v"(b));
    return d;
}
__device__ __forceinline__ unsigned alignb(unsigned hi, unsigned lo){
    unsigned d;
    asm("v_alignbit_b32 %0, %1, %2, 16" : "=v"(d) : "v"(hi), "v"(lo));
    return d;
}
__device__ __forceinline__ unsigned cvtpk(float lo, float hi){
    unsigned d;
    asm("v_cvt_pk_bf16_f32 %0, %1, %2" : "=v"(d) : "v"(lo), "v"(hi));
    return d;
}
__device__ __forceinline__ unsigned wscan_incl(unsigned v, int lane){
    #pragma unroll
    for (int o = 1; o < 64; o <<= 1){
        unsigned u = __shfl_up(v, o);
        v += (lane >= o) ? u : 0u;
    }
    return v;
}

// MFMA types
typedef short bf16x8 __attribute__((ext_vector_type(8)));
typedef float f32x4  __attribute__((ext_vector_type(4)));
__device__ __forceinline__ bf16x8 tofrag(uint4 q){
    union { uint4 q; bf16x8 f; } u; u.q = q; return u.f;
}

// ============================ K1f (unchanged from R8) ============================
__global__ __launch_bounds__(512, 6) void k1f(
    const float* __restrict__ x,
    unsigned short* __restrict__ outp, unsigned short* __restrict__ m64g,
    float g1, float q2, float q3, float q4, float q5, float q6)
{
    __shared__ __align__(16) unsigned short C0[16384];
    __shared__ __align__(16) unsigned short H5s[8192];
    __shared__ unsigned hist[1024];
    __shared__ unsigned wsum[8];
    __shared__ unsigned redA[8], redB[8];
    __shared__ unsigned s_dA, s_dB, s_cloA, s_cloB, s_keyA, s_keyB;

    const int tid = threadIdx.x;
    const int lane = tid & 63;
    const int wid = tid >> 6;
    const unsigned bc = blockIdx.x;
    const float4* xp4 = (const float4*)(x + (size_t)bc * HW_);

    unsigned key[32];

    #pragma unroll
    for (int k = 0; k < 2; ++k) hist[tid + k * 512] = 0u;
    __syncthreads();
    #pragma unroll
    for (int k = 0; k < 8; ++k){
        float4 v = xp4[tid + k * 512];
        key[4*k+0] = f2key(v.x);
        key[4*k+1] = f2key(v.y);
        key[4*k+2] = f2key(v.z);
        key[4*k+3] = f2key(v.w);
        atomicAdd(&hist[key[4*k+0] >> 22], 1u);
        atomicAdd(&hist[key[4*k+1] >> 22], 1u);
        atomicAdd(&hist[key[4*k+2] >> 22], 1u);
        atomicAdd(&hist[key[4*k+3] >> 22], 1u);
    }
    __syncthreads();

    unsigned rA = 15563u, rB = 15564u;
    unsigned prefVal = 0u, prefMask = 0u;
    bool done = false;

    {
        unsigned part = hist[tid*2] + hist[tid*2+1];
        unsigned incl = wscan_incl(part, lane);
        if (lane == 63) wsum[wid] = incl;
        __syncthreads();
        unsigned off = 0;
        #pragma unroll
        for (int w = 0; w < 8; ++w) off += (w < wid) ? wsum[w] : 0u;
        unsigned phi = incl + off;
        unsigned plo = phi - part;
        if (rA >= plo && rA < phi){
            unsigned c = plo;
            #pragma unroll
            for (int k = 0; k < 2; ++k){
                unsigned hh = hist[tid*2+k];
                if (rA < c + hh){ s_dA = tid*2+k; s_cloA = c; break; }
                c += hh;
            }
        }
        if (rB >= plo && rB < phi){
            unsigned c = plo;
            #pragma unroll
            for (int k = 0; k < 2; ++k){
                unsigned hh = hist[tid*2+k];
                if (rB < c + hh){ s_dB = tid*2+k; s_cloB = c; break; }
                c += hh;
            }
        }
        __syncthreads();
        unsigned dA = s_dA, dB = s_dB;
        if (dA != dB){
            unsigned locA = 0u, locB = 0xFFFFFFFFu;
            #pragma unroll
            for (int e = 0; e < 32; ++e){
                unsigned d = key[e] >> 22;
                if (d == dA) locA = max(locA, key[e]);
                if (d == dB) locB = min(locB, key[e]);
            }
            #pragma unroll
            for (int o = 32; o > 0; o >>= 1){
                locA = max(locA, __shfl_down(locA, o));
                locB = min(locB, __shfl_down(locB, o));
            }
            if (lane == 0){ redA[wid] = locA; redB[wid] = locB; }
            __syncthreads();
            if (tid == 0){
                unsigned a = redA[0], b = redB[0];
                for (int w = 1; w < 8; ++w){ a = max(a, redA[w]); b = min(b, redB[w]); }
                s_keyA = a; s_keyB = b;
            }
            __syncthreads();
            done = true;
        } else {
            prefVal = dA << 22; prefMask = 0x3FFu << 22;
            rA -= s_cloA; rB -= s_cloB;
            __syncthreads();
        }
    }

    if (!done){
        const int shifts[3] = {14, 6, 0};
        const int bitsv[3]  = {8, 8, 6};
        for (int lvl = 0; lvl < 3 && !done; ++lvl){
            int shift = shifts[lvl];
            unsigned nb = 1u << bitsv[lvl];
            unsigned msk = nb - 1u;
            if (tid < (int)nb) hist[tid] = 0u;
            __syncthreads();
            #pragma unroll
            for (int e = 0; e < 32; ++e){
                if ((key[e] & prefMask) == prefVal)
                    atomicAdd(&hist[(key[e] >> shift) & msk], 1u);
            }
            __syncthreads();
            unsigned part = (tid < (int)nb) ? hist[tid] : 0u;
            unsigned incl = wscan_incl(part, lane);
            if (lane == 63) wsum[wid] = incl;
            __syncthreads();
            unsigned off = 0;
            #pragma unroll
            for (int w = 0; w < 8; ++w) off += (w < wid) ? wsum[w] : 0u;
            unsigned phi = incl + off;
            unsigned plo = phi - part;
            if (tid < (int)nb){
                if (rA >= plo && rA < phi){ s_dA = tid; s_cloA = plo; }
                if (rB >= plo && rB < phi){ s_dB = tid; s_cloB = plo; }
            }
            __syncthreads();
            unsigned dA = s_dA, dB = s_dB;
            if (dA != dB){
                unsigned mA = prefMask | (msk << shift);
                unsigned vAp = prefVal | (dA << shift);
                unsigned vBp = prefVal | (dB << shift);
                unsigned locA = 0u, locB = 0xFFFFFFFFu;
                #pragma unroll
                for (int e = 0; e < 32; ++e){
                    if ((key[e] & mA) == vAp) locA = max(locA, key[e]);
                    if ((key[e] & mA) == vBp) locB = min(locB, key[e]);
                }
                #pragma unroll
                for (int o = 32; o > 0; o >>= 1){
                    locA = max(locA, __shfl_down(locA, o));
                    locB = min(locB, __shfl_down(locB, o));
                }
                if (lane == 0){ redA[wid] = locA; redB[wid] = locB; }
                __syncthreads();
                if (tid == 0){
                    unsigned a = redA[0], b = redB[0];
                    for (int w = 1; w < 8; ++w){ a = max(a, redA[w]); b = min(b, redB[w]); }
                    s_keyA = a; s_keyB = b;
                }
                __syncthreads();
                done = true;
            } else {
                prefVal |= dA << shift;
                prefMask |= msk << shift;
                rA -= s_cloA; rB -= s_cloB;
                if (lvl == 2){
                    if (tid == 0){ s_keyA = prefVal; s_keyB = prefVal; }
                    done = true;
                }
                __syncthreads();
            }
        }
    }

    float vlo = key2f(s_keyA);
    float vhi = key2f(s_keyB);
    float idxq = 0.95f * 16383.0f;
    float frac = idxq - floorf(idxq);
    const float thr = vlo * (1.0f - frac) + vhi * frac;

    #pragma unroll
    for (int k = 0; k < 8; ++k){
        int i = tid + k * 512;
        float f0 = key2f(key[4*k+0]); f0 = (f0 >= thr) ? f0 : 0.0f;
        float f1 = key2f(key[4*k+1]); f1 = (f1 >= thr) ? f1 : 0.0f;
        float f2 = key2f(key[4*k+2]); f2 = (f2 >= thr) ? f2 : 0.0f;
        float f3 = key2f(key[4*k+3]); f3 = (f3 >= thr) ? f3 : 0.0f;
        uint2 w; w.x = cvtpk(f0, f1); w.y = cvtpk(f2, f3);
        ((uint2*)C0)[i] = w;
    }
    __syncthreads();

    {
        const unsigned* C0w = (const unsigned*)C0;
        unsigned* outp32 = (unsigned*)(outp + (size_t)bc * HW_);
        const int wc = lane;
        const int r0 = wid * 16;

        unsigned hmA, hmB, hmC, cB, cC;
        {
            int r = r0 - 1;
            if (r < 0){ hmA = 0u; }
            else {
                unsigned w = C0w[r*64 + wc];
                unsigned wl = __shfl_up(w, 1);
                unsigned wr = __shfl_down(w, 1);
                if (wc == 0)  wl = 0u;
                if (wc == 63) wr = 0u;
                hmA = pkmax(pkmax(alignb(w, wl), w), alignb(wr, w));
            }
        }
        {
            int r = r0;
            unsigned w = C0w[r*64 + wc];
            unsigned wl = __shfl_up(w, 1);
            unsigned wr = __shfl_down(w, 1);
            if (wc == 0)  wl = 0u;
            if (wc == 63) wr = 0u;
            hmB = pkmax(pkmax(alignb(w, wl), w), alignb(wr, w));
            cB = w;
        }
        #pragma unroll
        for (int rr = 0; rr < 16; ++rr){
            int r = r0 + rr;
            {
                int rn = r + 1;
                if (rn > 127){ hmC = 0u; cC = 0u; }
                else {
                    unsigned w = C0w[rn*64 + wc];
                    unsigned wl = __shfl_up(w, 1);
                    unsigned wr = __shfl_down(w, 1);
                    if (wc == 0)  wl = 0u;
                    if (wc == 63) wr = 0u;
                    hmC = pkmax(pkmax(alignb(w, wl), w), alignb(wr, w));
                    cC = w;
                }
            }
            unsigned p1 = pkmax(pkmax(hmA, hmB), hmC);
            float a0 = g1 * bf2f((unsigned short)(p1 & 0xFFFFu));
            float a1v = g1 * bf2f((unsigned short)(p1 >> 16));
            outp32[r*64 + wc] = pkmax(cB, cvtpk(a0, a1v));
            unsigned wjm1 = __shfl_up(p1, 1);
            unsigned wjp1 = __shfl_down(p1, 1);
            if (wc == 0)  wjm1 = 0u;
            if (wc == 63) wjp1 = 0u;
            unsigned s = pkmax(wjm1, p1);
            s = pkmax(s, s >> 16);
            s = pkmax(s, wjp1 & 0xFFFFu);
            H5s[r*64 + wc] = (unsigned short)s;
            hmA = hmB; hmB = hmC; cB = cC;
        }
    }
    __syncthreads();

    unsigned* U = (unsigned*)C0;
    unsigned* T = ((unsigned*)C0) + 2048;
    float mf[8];
    #pragma unroll
    for (int k = 0; k < 4; ++k){
        int q = tid + k * 512;
        int i = q >> 5, wj = q & 31;
        int rr = 2 * i;
        const unsigned* H5w = (const unsigned*)H5s;
        unsigned m = pkmax(H5w[rr*32 + wj], H5w[(rr+1)*32 + wj]);
        if (rr >= 1) m = pkmax(m, H5w[(rr-1)*32 + wj]);
        if (rr >= 2) m = pkmax(m, H5w[(rr-2)*32 + wj]);
        if (rr + 2 <= 127) m = pkmax(m, H5w[(rr+2)*32 + wj]);
        U[q] = m;
        mf[2*k]   = q2 * bf2f((unsigned short)(m & 0xFFFFu));
        mf[2*k+1] = q2 * bf2f((unsigned short)(m >> 16));
    }
    __syncthreads();

    const float gs[4] = {q3, q4, q5, q6};
    #pragma unroll
    for (int it = 0; it < 4; ++it){
        #pragma unroll
        for (int k = 0; k < 4; ++k){
            int q = tid + k * 512;
            unsigned w = U[q];
            unsigned wl = __shfl_up(w, 1);
            unsigned wr = __shfl_down(w, 1);
            if ((q & 31) == 0)  wl = 0u;
            if ((q & 31) == 31) wr = 0u;
            T[q] = pkmax(pkmax(alignb(w, wl), w), alignb(wr, w));
        }
        __syncthreads();
        #pragma unroll
        for (int k = 0; k < 4; ++k){
            int q = tid + k * 512;
            int r = q >> 5;
            unsigned w = T[q];
            if (r > 0)  w = pkmax(w, T[q - 32]);
            if (r < 63) w = pkmax(w, T[q + 32]);
            U[q] = w;
            mf[2*k]   = fmaxf(mf[2*k],   gs[it] * bf2f((unsigned short)(w & 0xFFFFu)));
            mf[2*k+1] = fmaxf(mf[2*k+1], gs[it] * bf2f((unsigned short)(w >> 16)));
        }
        __syncthreads();
    }

    {
        unsigned* mp = (unsigned*)(m64g + (size_t)bc * 4096);
        #pragma unroll
        for (int k = 0; k < 4; ++k){
            int q = tid + k * 512;
            mp[q] = cvtpk(mf[2*k], mf[2*k+1]);
        }
    }
}

// ============================ K3: MFMA MLP ============================
// Per block: 64 px of one batch, all 256 channels. 256 threads = 4 waves,
// wave w owns px sub-tile [w*16, w*16+16).
// GEMM1: h[16mid x 16px] = (W1hi+W1lo)[16x256] x out'[256 x 16px], 8 Ksteps x 2 MFMA.
// GEMM2: R[16ch x 16px] per ch-tile = (W2hi+W2lo)[16x16pad32] x (hhi+hlo), 3 MFMA.
// Weights split hi/lo bf16 -> f32-level accuracy.
__global__ __launch_bounds__(256) void k3_mfma(
    const float* __restrict__ x, const unsigned short* __restrict__ outp,
    const unsigned short* __restrict__ m64,
    const float* __restrict__ w1, const float* __restrict__ b1,
    const float* __restrict__ w2, const float* __restrict__ b2,
    float* __restrict__ y)
{
    __shared__ __align__(16) unsigned short SOUT[16384];   // 32KB [64px][256ch] bf16, byte ^= (px&30)<<3
    __shared__ __align__(16) unsigned short W1h[16*264];   // 8.25KB, row stride 528B (16B mult)
    __shared__ __align__(16) unsigned short W1l[16*264];
    __shared__ __align__(16) unsigned short W2s[256*40];   // 20KB: [ch][0:16]=hi, [16:32]=lo, 8 pad
    __shared__ __align__(16) float HS[4*16*18];            // 4.5KB h f32 [wave][px][mid], stride 18

    const int tid  = threadIdx.x;
    const int lane = tid & 63;
    const int wid  = tid >> 6;
    const int blk  = blockIdx.x;
    const int b    = blk >> 8;
    const int px0  = (blk & 255) * 64;

    // ---- stage W1 hi/lo ----
    for (int e = tid; e < 4096; e += 256){
        int m = e >> 8, c = e & 255;
        float f = w1[m*256 + c];
        unsigned short hi = f2bf(f);
        W1h[m*264 + c] = hi;
        W1l[m*264 + c] = f2bf(f - bf2f(hi));
    }
    // ---- stage W2 hi/lo ----
    for (int e = tid; e < 4096; e += 256){
        int c = e >> 4, m = e & 15;
        float f = w2[e];
        unsigned short hi = f2bf(f);
        W2s[c*40 + m]      = hi;
        W2s[c*40 + 16 + m] = f2bf(f - bf2f(hi));
    }
    // ---- stage out' = max(outp, m64up), transposed [px][ch], swizzled ----
    {
        const int row = px0 >> 7;
        const int mibase = (row >> 1)*64 + ((px0 & 127) >> 1);
        const unsigned* op32 = (const unsigned*)(outp + (size_t)b*256*HW_);
        const unsigned short* mp = m64 + (size_t)b*256*4096;
        #pragma unroll
        for (int i = 0; i < 32; ++i){
            int u = tid + i*256;
            int ch = u >> 5, pxp = u & 31;
            unsigned o2 = op32[(ch*HW_ + px0)/2 + pxp];
            unsigned short mv = mp[ch*4096 + mibase + pxp];
            unsigned v = pkmax(o2, (unsigned)mv * 0x10001u);
            int pa = 2*pxp, pb = pa + 1;
            SOUT[(pa*512 + ((ch*2) ^ ((pa & 30) << 3))) >> 1] = (unsigned short)v;
            SOUT[(pb*512 + ((ch*2) ^ ((pb & 30) << 3))) >> 1] = (unsigned short)(v >> 16);
        }
    }
    __syncthreads();

    const int nidx = lane & 15;          // px col within wave tile / M row for A
    const int kg   = lane >> 4;          // k-group
    const int px_t = wid*16 + nidx;      // tile-local px (B/D column)

    // ---- GEMM1: h = (W1hi+W1lo) x out' ----
    f32x4 acc = {0.f, 0.f, 0.f, 0.f};
    #pragma unroll
    for (int ks = 0; ks < 8; ++ks){
        int byteB = px_t*512 + ((ks*64 + kg*16) ^ ((px_t & 30) << 3));
        uint4 qb = *(const uint4*)((const char*)SOUT + byteB);
        bf16x8 fb = tofrag(qb);
        int byteA = nidx*528 + ks*64 + kg*16;
        uint4 qh = *(const uint4*)((const char*)W1h + byteA);
        uint4 ql = *(const uint4*)((const char*)W1l + byteA);
        acc = __builtin_amdgcn_mfma_f32_16x16x32_bf16(tofrag(qh), fb, acc, 0, 0, 0);
        acc = __builtin_amdgcn_mfma_f32_16x16x32_bf16(tofrag(ql), fb, acc, 0, 0, 0);
    }
    // h = relu(acc + b1); D1: col=lane&15=px, row=mid=kg*4+i
    #pragma unroll
    for (int i2 = 0; i2 < 4; ++i2){
        int mid = kg*4 + i2;
        float hv = fmaxf(acc[i2] + b1[mid], 0.0f);
        HS[(wid*16 + nidx)*18 + mid] = hv;
    }
    __syncthreads();

    // ---- build B2 frags from h (hi/lo) ----
    bf16x8 bh = {0,0,0,0,0,0,0,0}, bl = {0,0,0,0,0,0,0,0};
    if (kg < 2){
        const float* hp = &HS[(wid*16 + nidx)*18 + kg*8];
        float f0 = hp[0], f1 = hp[1], f2 = hp[2], f3 = hp[3];
        float f4 = hp[4], f5 = hp[5], f6 = hp[6], f7 = hp[7];
        unsigned short h0 = f2bf(f0), h1 = f2bf(f1), h2 = f2bf(f2), h3 = f2bf(f3);
        unsigned short h4 = f2bf(f4), h5 = f2bf(f5), h6 = f2bf(f6), h7 = f2bf(f7);
        bh[0] = (short)h0; bh[1] = (short)h1; bh[2] = (short)h2; bh[3] = (short)h3;
        bh[4] = (short)h4; bh[5] = (short)h5; bh[6] = (short)h6; bh[7] = (short)h7;
        bl[0] = (short)f2bf(f0 - bf2f(h0)); bl[1] = (short)f2bf(f1 - bf2f(h1));
        bl[2] = (short)f2bf(f2 - bf2f(h2)); bl[3] = (short)f2bf(f3 - bf2f(h3));
        bl[4] = (short)f2bf(f4 - bf2f(h4)); bl[5] = (short)f2bf(f5 - bf2f(h5));
        bl[6] = (short)f2bf(f6 - bf2f(h6)); bl[7] = (short)f2bf(f7 - bf2f(h7));
    }

    // ---- GEMM2 + epilogue per 16-channel tile ----
    #pragma unroll 4
    for (int t = 0; t < 16; ++t){
        bf16x8 a2h = {0,0,0,0,0,0,0,0}, a2l = {0,0,0,0,0,0,0,0};
        if (kg < 2){
            const char* basep = (const char*)W2s + (t*16 + nidx)*80;
            a2h = tofrag(*(const uint4*)(basep + kg*16));
            a2l = tofrag(*(const uint4*)(basep + 32 + kg*16));
        }
        f32x4 d2 = {0.f, 0.f, 0.f, 0.f};
        d2 = __builtin_amdgcn_mfma_f32_16x16x32_bf16(a2h, bh, d2, 0, 0, 0);
        d2 = __builtin_amdgcn_mfma_f32_16x16x32_bf16(a2l, bh, d2, 0, 0, 0);
        d2 = __builtin_amdgcn_mfma_f32_16x16x32_bf16(a2h, bl, d2, 0, 0, 0);
        // D2: col=px (lane&15), rows ch = t*16 + kg*4 + i
        #pragma unroll
        for (int i2 = 0; i2 < 4; ++i2){
            int ch = t*16 + kg*4 + i2;
            float logit = d2[i2] + b2[ch];
            float R = 1.0f / (1.0f + __expf(-logit));
            size_t gidx = ((size_t)(b*256 + ch))*HW_ + px0 + px_t;
            y[gidx] = x[gidx] * R;
        }
    }
}

extern "C" void kernel_launch(void* const* d_in, const int* in_sizes, int n_in,
                              void* d_out, int out_size, void* d_ws, size_t ws_size,
                              hipStream_t stream) {
    const float* x  = (const float*)d_in[0];
    const float* w1 = (const float*)d_in[1];
    const float* b1 = (const float*)d_in[2];
    const float* w2 = (const float*)d_in[3];
    const float* b2 = (const float*)d_in[4];
    float* y  = (float*)d_out;
    char* ws = (char*)d_ws;

    unsigned short* outp = (unsigned short*)ws;                 // 134 MB
    unsigned short* m64  = (unsigned short*)(ws + 134217728);   // 33.5 MB

    float g1 = 0.99f;
    float q2 = (float)std::pow(0.99, 3.0);
    float q3 = (float)std::pow(0.99, 7.0);
    float q4 = (float)std::pow(0.99, 15.0);
    float q5 = (float)std::pow(0.99, 31.0);
    float q6 = (float)std::pow(0.99, 63.0);

    k1f<<<4096, 512, 0, stream>>>(x, outp, m64, g1, q2, q3, q4, q5, q6);
    k3_mfma<<<4096, 256, 0, stream>>>(x, outp, m64, w1, b1, w2, b2, y);
}

// Round 10
// 336.442 us; speedup vs baseline: 1.0381x; 1.0381x over previous
//
#include <hip/hip_runtime.h>
#include <cmath>
#include <cfloat>

#define HW_ 16384

__device__ __forceinline__ unsigned f2key(float f){
    unsigned u = __float_as_uint(f);
    return u ^ ((u & 0x80000000u) ? 0xFFFFFFFFu : 0x80000000u);
}
__device__ __forceinline__ float key2f(unsigned k){
    unsigned u = (k & 0x80000000u) ? (k ^ 0x80000000u) : ~k;
    return __uint_as_float(u);
}
__device__ __forceinline__ unsigned short f2bf(float f){
    unsigned u = __float_as_uint(f);
    unsigned r = u + 0x7FFFu + ((u >> 16) & 1u);
    return (unsigned short)(r >> 16);
}
__device__ __forceinline__ float bf2f(unsigned short s){
    return __uint_as_float((unsigned)s << 16);
}
// packed helpers (bf16 pairs in u32; all pooled values >= 0 so u16 order == float order)
__device__ __forceinline__ unsigned pkmax(unsigned a, unsigned b){
    unsigned d;
    asm("v_pk_max_u16 %0, %1, %2" : "=v"(d) : "v"(a), "v"(b));
    return d;
}
__device__ __forceinline__ unsigned alignb(unsigned hi, unsigned lo){
    unsigned d;
    asm("v_alignbit_b32 %0, %1, %2, 16" : "=v"(d) : "v"(hi), "v"(lo));
    return d;
}
__device__ __forceinline__ unsigned cvtpk(float lo, float hi){
    unsigned d;
    asm("v_cvt_pk_bf16_f32 %0, %1, %2" : "=v"(d) : "v"(lo), "v"(hi));
    return d;
}
__device__ __forceinline__ unsigned wscan_incl(unsigned v, int lane){
    #pragma unroll
    for (int o = 1; o < 64; o <<= 1){
        unsigned u = __shfl_up(v, o);
        v += (lane >= o) ? u : 0u;
    }
    return v;
}

// MFMA types
typedef short bf16x8 __attribute__((ext_vector_type(8)));
typedef float f32x4  __attribute__((ext_vector_type(4)));
__device__ __forceinline__ bf16x8 tofrag(uint4 q){
    union { uint4 q; bf16x8 f; } u; u.q = q; return u.f;
}

// ============================ K0: weight hi/lo split (runs once) ============================
__global__ __launch_bounds__(256) void k0_split(
    const float* __restrict__ w1, const float* __restrict__ w2,
    unsigned short* __restrict__ W1h, unsigned short* __restrict__ W1l,
    unsigned short* __restrict__ W2h, unsigned short* __restrict__ W2l)
{
    int e = blockIdx.x * 256 + threadIdx.x;   // 0..8191
    if (e < 4096){
        float f = w1[e];                       // [16][256] row-major
        unsigned short hi = f2bf(f);
        W1h[e] = hi;
        W1l[e] = f2bf(f - bf2f(hi));
    } else {
        int e2 = e - 4096;
        float f = w2[e2];                      // [256][16] row-major
        unsigned short hi = f2bf(f);
        W2h[e2] = hi;
        W2l[e2] = f2bf(f - bf2f(hi));
    }
}

// ============================ K1f (unchanged from R8) ============================
__global__ __launch_bounds__(512, 6) void k1f(
    const float* __restrict__ x,
    unsigned short* __restrict__ outp, unsigned short* __restrict__ m64g,
    float g1, float q2, float q3, float q4, float q5, float q6)
{
    __shared__ __align__(16) unsigned short C0[16384];
    __shared__ __align__(16) unsigned short H5s[8192];
    __shared__ unsigned hist[1024];
    __shared__ unsigned wsum[8];
    __shared__ unsigned redA[8], redB[8];
    __shared__ unsigned s_dA, s_dB, s_cloA, s_cloB, s_keyA, s_keyB;

    const int tid = threadIdx.x;
    const int lane = tid & 63;
    const int wid = tid >> 6;
    const unsigned bc = blockIdx.x;
    const float4* xp4 = (const float4*)(x + (size_t)bc * HW_);

    unsigned key[32];

    #pragma unroll
    for (int k = 0; k < 2; ++k) hist[tid + k * 512] = 0u;
    __syncthreads();
    #pragma unroll
    for (int k = 0; k < 8; ++k){
        float4 v = xp4[tid + k * 512];
        key[4*k+0] = f2key(v.x);
        key[4*k+1] = f2key(v.y);
        key[4*k+2] = f2key(v.z);
        key[4*k+3] = f2key(v.w);
        atomicAdd(&hist[key[4*k+0] >> 22], 1u);
        atomicAdd(&hist[key[4*k+1] >> 22], 1u);
        atomicAdd(&hist[key[4*k+2] >> 22], 1u);
        atomicAdd(&hist[key[4*k+3] >> 22], 1u);
    }
    __syncthreads();

    unsigned rA = 15563u, rB = 15564u;
    unsigned prefVal = 0u, prefMask = 0u;
    bool done = false;

    {
        unsigned part = hist[tid*2] + hist[tid*2+1];
        unsigned incl = wscan_incl(part, lane);
        if (lane == 63) wsum[wid] = incl;
        __syncthreads();
        unsigned off = 0;
        #pragma unroll
        for (int w = 0; w < 8; ++w) off += (w < wid) ? wsum[w] : 0u;
        unsigned phi = incl + off;
        unsigned plo = phi - part;
        if (rA >= plo && rA < phi){
            unsigned c = plo;
            #pragma unroll
            for (int k = 0; k < 2; ++k){
                unsigned hh = hist[tid*2+k];
                if (rA < c + hh){ s_dA = tid*2+k; s_cloA = c; break; }
                c += hh;
            }
        }
        if (rB >= plo && rB < phi){
            unsigned c = plo;
            #pragma unroll
            for (int k = 0; k < 2; ++k){
                unsigned hh = hist[tid*2+k];
                if (rB < c + hh){ s_dB = tid*2+k; s_cloB = c; break; }
                c += hh;
            }
        }
        __syncthreads();
        unsigned dA = s_dA, dB = s_dB;
        if (dA != dB){
            unsigned locA = 0u, locB = 0xFFFFFFFFu;
            #pragma unroll
            for (int e = 0; e < 32; ++e){
                unsigned d = key[e] >> 22;
                if (d == dA) locA = max(locA, key[e]);
                if (d == dB) locB = min(locB, key[e]);
            }
            #pragma unroll
            for (int o = 32; o > 0; o >>= 1){
                locA = max(locA, __shfl_down(locA, o));
                locB = min(locB, __shfl_down(locB, o));
            }
            if (lane == 0){ redA[wid] = locA; redB[wid] = locB; }
            __syncthreads();
            if (tid == 0){
                unsigned a = redA[0], b = redB[0];
                for (int w = 1; w < 8; ++w){ a = max(a, redA[w]); b = min(b, redB[w]); }
                s_keyA = a; s_keyB = b;
            }
            __syncthreads();
            done = true;
        } else {
            prefVal = dA << 22; prefMask = 0x3FFu << 22;
            rA -= s_cloA; rB -= s_cloB;
            __syncthreads();
        }
    }

    if (!done){
        const int shifts[3] = {14, 6, 0};
        const int bitsv[3]  = {8, 8, 6};
        for (int lvl = 0; lvl < 3 && !done; ++lvl){
            int shift = shifts[lvl];
            unsigned nb = 1u << bitsv[lvl];
            unsigned msk = nb - 1u;
            if (tid < (int)nb) hist[tid] = 0u;
            __syncthreads();
            #pragma unroll
            for (int e = 0; e < 32; ++e){
                if ((key[e] & prefMask) == prefVal)
                    atomicAdd(&hist[(key[e] >> shift) & msk], 1u);
            }
            __syncthreads();
            unsigned part = (tid < (int)nb) ? hist[tid] : 0u;
            unsigned incl = wscan_incl(part, lane);
            if (lane == 63) wsum[wid] = incl;
            __syncthreads();
            unsigned off = 0;
            #pragma unroll
            for (int w = 0; w < 8; ++w) off += (w < wid) ? wsum[w] : 0u;
            unsigned phi = incl + off;
            unsigned plo = phi - part;
            if (tid < (int)nb){
                if (rA >= plo && rA < phi){ s_dA = tid; s_cloA = plo; }
                if (rB >= plo && rB < phi){ s_dB = tid; s_cloB = plo; }
            }
            __syncthreads();
            unsigned dA = s_dA, dB = s_dB;
            if (dA != dB){
                unsigned mA = prefMask | (msk << shift);
                unsigned vAp = prefVal | (dA << shift);
                unsigned vBp = prefVal | (dB << shift);
                unsigned locA = 0u, locB = 0xFFFFFFFFu;
                #pragma unroll
                for (int e = 0; e < 32; ++e){
                    if ((key[e] & mA) == vAp) locA = max(locA, key[e]);
                    if ((key[e] & mA) == vBp) locB = min(locB, key[e]);
                }
                #pragma unroll
                for (int o = 32; o > 0; o >>= 1){
                    locA = max(locA, __shfl_down(locA, o));
                    locB = min(locB, __shfl_down(locB, o));
                }
                if (lane == 0){ redA[wid] = locA; redB[wid] = locB; }
                __syncthreads();
                if (tid == 0){
                    unsigned a = redA[0], b = redB[0];
                    for (int w = 1; w < 8; ++w){ a = max(a, redA[w]); b = min(b, redB[w]); }
                    s_keyA = a; s_keyB = b;
                }
                __syncthreads();
                done = true;
            } else {
                prefVal |= dA << shift;
                prefMask |= msk << shift;
                rA -= s_cloA; rB -= s_cloB;
                if (lvl == 2){
                    if (tid == 0){ s_keyA = prefVal; s_keyB = prefVal; }
                    done = true;
                }
                __syncthreads();
            }
        }
    }

    float vlo = key2f(s_keyA);
    float vhi = key2f(s_keyB);
    float idxq = 0.95f * 16383.0f;
    float frac = idxq - floorf(idxq);
    const float thr = vlo * (1.0f - frac) + vhi * frac;

    #pragma unroll
    for (int k = 0; k < 8; ++k){
        int i = tid + k * 512;
        float f0 = key2f(key[4*k+0]); f0 = (f0 >= thr) ? f0 : 0.0f;
        float f1 = key2f(key[4*k+1]); f1 = (f1 >= thr) ? f1 : 0.0f;
        float f2 = key2f(key[4*k+2]); f2 = (f2 >= thr) ? f2 : 0.0f;
        float f3 = key2f(key[4*k+3]); f3 = (f3 >= thr) ? f3 : 0.0f;
        uint2 w; w.x = cvtpk(f0, f1); w.y = cvtpk(f2, f3);
        ((uint2*)C0)[i] = w;
    }
    __syncthreads();

    {
        const unsigned* C0w = (const unsigned*)C0;
        unsigned* outp32 = (unsigned*)(outp + (size_t)bc * HW_);
        const int wc = lane;
        const int r0 = wid * 16;

        unsigned hmA, hmB, hmC, cB, cC;
        {
            int r = r0 - 1;
            if (r < 0){ hmA = 0u; }
            else {
                unsigned w = C0w[r*64 + wc];
                unsigned wl = __shfl_up(w, 1);
                unsigned wr = __shfl_down(w, 1);
                if (wc == 0)  wl = 0u;
                if (wc == 63) wr = 0u;
                hmA = pkmax(pkmax(alignb(w, wl), w), alignb(wr, w));
            }
        }
        {
            int r = r0;
            unsigned w = C0w[r*64 + wc];
            unsigned wl = __shfl_up(w, 1);
            unsigned wr = __shfl_down(w, 1);
            if (wc == 0)  wl = 0u;
            if (wc == 63) wr = 0u;
            hmB = pkmax(pkmax(alignb(w, wl), w), alignb(wr, w));
            cB = w;
        }
        #pragma unroll
        for (int rr = 0; rr < 16; ++rr){
            int r = r0 + rr;
            {
                int rn = r + 1;
                if (rn > 127){ hmC = 0u; cC = 0u; }
                else {
                    unsigned w = C0w[rn*64 + wc];
                    unsigned wl = __shfl_up(w, 1);
                    unsigned wr = __shfl_down(w, 1);
                    if (wc == 0)  wl = 0u;
                    if (wc == 63) wr = 0u;
                    hmC = pkmax(pkmax(alignb(w, wl), w), alignb(wr, w));
                    cC = w;
                }
            }
            unsigned p1 = pkmax(pkmax(hmA, hmB), hmC);
            float a0 = g1 * bf2f((unsigned short)(p1 & 0xFFFFu));
            float a1v = g1 * bf2f((unsigned short)(p1 >> 16));
            outp32[r*64 + wc] = pkmax(cB, cvtpk(a0, a1v));
            unsigned wjm1 = __shfl_up(p1, 1);
            unsigned wjp1 = __shfl_down(p1, 1);
            if (wc == 0)  wjm1 = 0u;
            if (wc == 63) wjp1 = 0u;
            unsigned s = pkmax(wjm1, p1);
            s = pkmax(s, s >> 16);
            s = pkmax(s, wjp1 & 0xFFFFu);
            H5s[r*64 + wc] = (unsigned short)s;
            hmA = hmB; hmB = hmC; cB = cC;
        }
    }
    __syncthreads();

    unsigned* U = (unsigned*)C0;
    unsigned* T = ((unsigned*)C0) + 2048;
    float mf[8];
    #pragma unroll
    for (int k = 0; k < 4; ++k){
        int q = tid + k * 512;
        int i = q >> 5, wj = q & 31;
        int rr = 2 * i;
        const unsigned* H5w = (const unsigned*)H5s;
        unsigned m = pkmax(H5w[rr*32 + wj], H5w[(rr+1)*32 + wj]);
        if (rr >= 1) m = pkmax(m, H5w[(rr-1)*32 + wj]);
        if (rr >= 2) m = pkmax(m, H5w[(rr-2)*32 + wj]);
        if (rr + 2 <= 127) m = pkmax(m, H5w[(rr+2)*32 + wj]);
        U[q] = m;
        mf[2*k]   = q2 * bf2f((unsigned short)(m & 0xFFFFu));
        mf[2*k+1] = q2 * bf2f((unsigned short)(m >> 16));
    }
    __syncthreads();

    const float gs[4] = {q3, q4, q5, q6};
    #pragma unroll
    for (int it = 0; it < 4; ++it){
        #pragma unroll
        for (int k = 0; k < 4; ++k){
            int q = tid + k * 512;
            unsigned w = U[q];
            unsigned wl = __shfl_up(w, 1);
            unsigned wr = __shfl_down(w, 1);
            if ((q & 31) == 0)  wl = 0u;
            if ((q & 31) == 31) wr = 0u;
            T[q] = pkmax(pkmax(alignb(w, wl), w), alignb(wr, w));
        }
        __syncthreads();
        #pragma unroll
        for (int k = 0; k < 4; ++k){
            int q = tid + k * 512;
            int r = q >> 5;
            unsigned w = T[q];
            if (r > 0)  w = pkmax(w, T[q - 32]);
            if (r < 63) w = pkmax(w, T[q + 32]);
            U[q] = w;
            mf[2*k]   = fmaxf(mf[2*k],   gs[it] * bf2f((unsigned short)(w & 0xFFFFu)));
            mf[2*k+1] = fmaxf(mf[2*k+1], gs[it] * bf2f((unsigned short)(w >> 16)));
        }
        __syncthreads();
    }

    {
        unsigned* mp = (unsigned*)(m64g + (size_t)bc * 4096);
        #pragma unroll
        for (int k = 0; k < 4; ++k){
            int q = tid + k * 512;
            mp[q] = cvtpk(mf[2*k], mf[2*k+1]);
        }
    }
}

// ============================ K3: MFMA MLP v2 ============================
// 64 px/block, 256 thr = 4 waves (wave w -> px [w*16, w*16+16)).
// SOUT 32KB (word = ch-pair for one px, XOR-swizzled), HS 4.5KB -> 4 blocks/CU.
// Weight fragments read from pre-split global W1h/W1l/W2h/W2l (L1-hot).
__global__ __launch_bounds__(256) void k3_mfma(
    const float* __restrict__ x,
    const unsigned short* __restrict__ outp, const unsigned short* __restrict__ m64,
    const unsigned short* __restrict__ W1h, const unsigned short* __restrict__ W1l,
    const unsigned short* __restrict__ W2h, const unsigned short* __restrict__ W2l,
    const float* __restrict__ b1, const float* __restrict__ b2,
    float* __restrict__ y)
{
    __shared__ __align__(16) unsigned SOUT32[8192];   // [64px][128 ch-pair words], swizzled
    __shared__ __align__(16) float HS[4*16*18];       // h f32 [px][mid], stride 18

    const int tid  = threadIdx.x;
    const int lane = tid & 63;
    const int wid  = tid >> 6;
    const int blk  = blockIdx.x;
    const int b    = blk >> 8;
    const int px0  = (blk & 255) * 64;

    // ---- stage out' = max(outp, m64up): repack channel-pairs per px, swizzled ----
    {
        const int row = px0 >> 7;
        const int mibase = (row >> 1)*64 + ((px0 & 127) >> 1);
        const unsigned* op32 = (const unsigned*)(outp + (size_t)b*256*HW_);
        const unsigned short* mp = m64 + (size_t)b*256*4096;
        #pragma unroll
        for (int i = 0; i < 16; ++i){
            int u = i*256 + tid;
            int c4 = u >> 5, pxp = u & 31;       // c4: ch pair 0..127, pxp: px pair 0..31
            int ch0 = 2*c4;
            unsigned wA = op32[ch0*(HW_/2) + px0/2 + pxp];
            unsigned wB = op32[(ch0+1)*(HW_/2) + px0/2 + pxp];
            unsigned mA = (unsigned)mp[ch0*4096 + mibase + pxp] * 0x10001u;
            unsigned mB = (unsigned)mp[(ch0+1)*4096 + mibase + pxp] * 0x10001u;
            unsigned va = pkmax(wA, mA);         // (out'[ch0][pa], out'[ch0][pb])
            unsigned vb = pkmax(wB, mB);
            unsigned wpa = (va & 0xFFFFu) | (vb << 16);        // (ch0,ch1) @ pa
            unsigned wpb = (va >> 16) | (vb & 0xFFFF0000u);    // (ch0,ch1) @ pb
            int sw = (pxp & 7) << 2;             // swizzle = ((px>>1)&7)<<2
            SOUT32[(2*pxp)  *128 + (c4 ^ sw)] = wpa;
            SOUT32[(2*pxp+1)*128 + (c4 ^ sw)] = wpb;
        }
    }
    __syncthreads();

    const int nidx = lane & 15;
    const int kg   = lane >> 4;
    const int px_t = wid*16 + nidx;
    const int sxz  = ((px_t >> 1) & 7) << 2;

    // ---- GEMM1: h = (W1hi+W1lo) x out' ----
    f32x4 acc = {0.f, 0.f, 0.f, 0.f};
    #pragma unroll
    for (int ks = 0; ks < 8; ++ks){
        int w0 = (ks*16 + kg*4) ^ sxz;
        bf16x8 fb = tofrag(*(const uint4*)&SOUT32[px_t*128 + w0]);
        bf16x8 ah = tofrag(*(const uint4*)(W1h + nidx*256 + ks*32 + kg*8));
        bf16x8 al = tofrag(*(const uint4*)(W1l + nidx*256 + ks*32 + kg*8));
        acc = __builtin_amdgcn_mfma_f32_16x16x32_bf16(ah, fb, acc, 0, 0, 0);
        acc = __builtin_amdgcn_mfma_f32_16x16x32_bf16(al, fb, acc, 0, 0, 0);
    }
    // h = relu(acc + b1); D1: col=lane&15=px, row=mid=kg*4+i
    #pragma unroll
    for (int i2 = 0; i2 < 4; ++i2){
        int mid = kg*4 + i2;
        float hv = fmaxf(acc[i2] + b1[mid], 0.0f);
        HS[(wid*16 + nidx)*18 + mid] = hv;
    }
    __syncthreads();

    // ---- B2 frags from h (hi/lo) ----
    bf16x8 bh = {0,0,0,0,0,0,0,0}, bl = {0,0,0,0,0,0,0,0};
    if (kg < 2){
        const float* hp = &HS[(wid*16 + nidx)*18 + kg*8];
        float f0 = hp[0], f1 = hp[1], f2 = hp[2], f3 = hp[3];
        float f4 = hp[4], f5 = hp[5], f6 = hp[6], f7 = hp[7];
        unsigned short h0 = f2bf(f0), h1 = f2bf(f1), h2 = f2bf(f2), h3 = f2bf(f3);
        unsigned short h4 = f2bf(f4), h5 = f2bf(f5), h6 = f2bf(f6), h7 = f2bf(f7);
        bh[0] = (short)h0; bh[1] = (short)h1; bh[2] = (short)h2; bh[3] = (short)h3;
        bh[4] = (short)h4; bh[5] = (short)h5; bh[6] = (short)h6; bh[7] = (short)h7;
        bl[0] = (short)f2bf(f0 - bf2f(h0)); bl[1] = (short)f2bf(f1 - bf2f(h1));
        bl[2] = (short)f2bf(f2 - bf2f(h2)); bl[3] = (short)f2bf(f3 - bf2f(h3));
        bl[4] = (short)f2bf(f4 - bf2f(h4)); bl[5] = (short)f2bf(f5 - bf2f(h5));
        bl[6] = (short)f2bf(f6 - bf2f(h6)); bl[7] = (short)f2bf(f7 - bf2f(h7));
    }

    // ---- GEMM2 + epilogue per 16-channel tile ----
    #pragma unroll 4
    for (int t = 0; t < 16; ++t){
        bf16x8 a2h = {0,0,0,0,0,0,0,0}, a2l = {0,0,0,0,0,0,0,0};
        if (kg < 2){
            a2h = tofrag(*(const uint4*)(W2h + (t*16 + nidx)*16 + kg*8));
            a2l = tofrag(*(const uint4*)(W2l + (t*16 + nidx)*16 + kg*8));
        }
        f32x4 d2 = {0.f, 0.f, 0.f, 0.f};
        d2 = __builtin_amdgcn_mfma_f32_16x16x32_bf16(a2h, bh, d2, 0, 0, 0);
        d2 = __builtin_amdgcn_mfma_f32_16x16x32_bf16(a2l, bh, d2, 0, 0, 0);
        d2 = __builtin_amdgcn_mfma_f32_16x16x32_bf16(a2h, bl, d2, 0, 0, 0);
        #pragma unroll
        for (int i2 = 0; i2 < 4; ++i2){
            int ch = t*16 + kg*4 + i2;
            float logit = d2[i2] + b2[ch];
            float R = 1.0f / (1.0f + __expf(-logit));
            size_t gidx = ((size_t)(b*256 + ch))*HW_ + px0 + px_t;
            y[gidx] = x[gidx] * R;
        }
    }
}

extern "C" void kernel_launch(void* const* d_in, const int* in_sizes, int n_in,
                              void* d_out, int out_size, void* d_ws, size_t ws_size,
                              hipStream_t stream) {
    const float* x  = (const float*)d_in[0];
    const float* w1 = (const float*)d_in[1];
    const float* b1 = (const float*)d_in[2];
    const float* w2 = (const float*)d_in[3];
    const float* b2 = (const float*)d_in[4];
    float* y  = (float*)d_out;
    char* ws = (char*)d_ws;

    unsigned short* outp = (unsigned short*)ws;                 // 134 MB
    unsigned short* m64  = (unsigned short*)(ws + 134217728);   // 33.5 MB
    unsigned short* W1h  = (unsigned short*)(ws + 167772160);
    unsigned short* W1l  = W1h + 4096;
    unsigned short* W2h  = W1h + 8192;
    unsigned short* W2l  = W1h + 12288;

    float g1 = 0.99f;
    float q2 = (float)std::pow(0.99, 3.0);
    float q3 = (float)std::pow(0.99, 7.0);
    float q4 = (float)std::pow(0.99, 15.0);
    float q5 = (float)std::pow(0.99, 31.0);
    float q6 = (float)std::pow(0.99, 63.0);

    k0_split<<<32, 256, 0, stream>>>(w1, w2, W1h, W1l, W2h, W2l);
    k1f<<<4096, 512, 0, stream>>>(x, outp, m64, g1, q2, q3, q4, q5, q6);
    k3_mfma<<<4096, 256, 0, stream>>>(x, outp, m64, W1h, W1l, W2h, W2l, b1, b2, y);
}